// Round 1
// baseline (162.669 us; speedup 1.0000x reference)
//
#include <hip/hip_runtime.h>

#define SEQ 2048
#define DD 128
#define HQ 32
#define HKV 8
#define WIN 512
#define QT 32

typedef unsigned short u16;
typedef unsigned int u32;
typedef __attribute__((ext_vector_type(8))) short bf16x8;
typedef __attribute__((ext_vector_type(4))) float f32x4;

__device__ __forceinline__ u16 f2bf(float f) {
  u32 u = __builtin_bit_cast(u32, f);
  u += 0x7FFFu + ((u >> 16) & 1u);
  return (u16)(u >> 16);
}

__device__ __forceinline__ void gl16(const void* g, void* l) {
  __builtin_amdgcn_global_load_lds(
      (const __attribute__((address_space(1))) void*)g,
      (__attribute__((address_space(3))) void*)l, 16, 0, 0);
}

// GroupRMSNorm + weight + (optional) softmax-scale fold + bf16 + repack to [b][h][s][d]
__global__ void __launch_bounds__(256) norm_kernel(
    const float* __restrict__ x, const float* __restrict__ w,
    u16* __restrict__ o, int hshift, float scale) {
  const int tid = threadIdx.x;
  const int lane = tid & 63;
  const int wv = tid >> 6;
  const int sub = lane >> 5;
  const int l5 = lane & 31;
  const int rid = blockIdx.x * 8 + wv * 2 + sub;   // flattened (b,s,h)
  const int H = 1 << hshift;
  const int hh = rid & (H - 1);
  const int s = (rid >> hshift) & (SEQ - 1);
  const int b = rid >> (hshift + 11);
  const float4 xv = *(reinterpret_cast<const float4*>(x + (size_t)rid * DD) + l5);
  float ssq = xv.x * xv.x + xv.y * xv.y + xv.z * xv.z + xv.w * xv.w;
  ssq += __shfl_xor(ssq, 1);
  ssq += __shfl_xor(ssq, 2);
  ssq += __shfl_xor(ssq, 4);
  ssq += __shfl_xor(ssq, 8);
  ssq += __shfl_xor(ssq, 16);
  const float inv = rsqrtf(ssq * (1.0f / 128.0f) + 1e-5f) * scale;
  const float4 wv4 = *(reinterpret_cast<const float4*>(w + hh * DD) + l5);
  const u16 o0 = f2bf(xv.x * inv * wv4.x);
  const u16 o1 = f2bf(xv.y * inv * wv4.y);
  const u16 o2 = f2bf(xv.z * inv * wv4.z);
  const u16 o3 = f2bf(xv.w * inv * wv4.w);
  const size_t oo = (((size_t)b * H + hh) * SEQ + s) * DD + l5 * 4;
  uint2 pk;
  pk.x = (u32)o0 | ((u32)o1 << 16);
  pk.y = (u32)o2 | ((u32)o3 << 16);
  *reinterpret_cast<uint2*>(o + oo) = pk;
}

// V: fp32 [b][s][h][d] -> bf16 transposed [b][h][d][s]
__global__ void __launch_bounds__(256) transv_kernel(
    const float* __restrict__ v, u16* __restrict__ vt) {
  const int bid = blockIdx.x;
  const int st = bid & 31;
  const int h = (bid >> 5) & 7;
  const int b = bid >> 8;
  const int sbase = st * 64;
  const int t = threadIdx.x;
  const int d = t & 127;
  const int sch = (t >> 7) * 32;
  const size_t oo = (((size_t)(b * HKV + h)) * DD + d) * SEQ + sbase + sch;
#pragma unroll
  for (int q8 = 0; q8 < 4; ++q8) {
    uint4 o;
    u32 c[4];
#pragma unroll
    for (int p = 0; p < 4; ++p) {
      const int ss0 = q8 * 8 + p * 2;
      const int s0 = sbase + sch + ss0;
      const float a0 = v[((size_t)(b * SEQ + s0) * HKV + h) * DD + d];
      const float a1 = v[((size_t)(b * SEQ + s0 + 1) * HKV + h) * DD + d];
      c[p] = (u32)f2bf(a0) | ((u32)f2bf(a1) << 16);
    }
    o.x = c[0]; o.y = c[1]; o.z = c[2]; o.w = c[3];
    *reinterpret_cast<uint4*>(vt + oo + q8 * 8) = o;
  }
}

__global__ void __launch_bounds__(256) attn_kernel(
    const u16* __restrict__ qn, const u16* __restrict__ kn,
    const u16* __restrict__ vt, float* __restrict__ out) {
  __shared__ char smem[49152];
  char* ldsK = smem;             // [64 keys][256B], 16B-chunk XOR-swizzled by row&7
  char* ldsV = smem + 16384;     // [128 dims][128B], swizzled
  const int tid = threadIdx.x;
  const int w = tid >> 6;
  const int lane = tid & 63;
  const int c = lane & 15;
  const int g = lane >> 4;
  char* ldsP = smem + 32768 + w * 4096;  // per-wave [32 rows][128B], swizzled

  const int bid = blockIdx.x;
  const int qt = bid & 63;
  const int hk = (bid >> 6) & 7;
  const int b = bid >> 9;
  const int i0 = qt * QT;
  const int h = hk * 4 + w;

  const u16* qb = qn + ((size_t)(b * HQ + h) * SEQ + i0) * DD;
  const u16* kbp = kn + (size_t)(b * HKV + hk) * SEQ * DD;
  const u16* vbp = vt + (size_t)(b * HKV + hk) * DD * SEQ;

  // Q fragments: A[row=c][k=g*8+j], 2 row-tiles x 4 k-tiles
  bf16x8 aq[2][4];
#pragma unroll
  for (int mt = 0; mt < 2; ++mt)
#pragma unroll
    for (int kt = 0; kt < 4; ++kt)
      aq[mt][kt] = *reinterpret_cast<const bf16x8*>(qb + (mt * 16 + c) * DD + kt * 32 + g * 8);

  int ks = i0 - WIN;
  ks = (ks < 0) ? 0 : (ks & ~63);
  const int ntl = (i0 + QT - ks + 63) >> 6;

  const float C_T = 3.70370370e-4f;       // 1/(3*CAP^2)
  const float LOG2E = 1.44269504088896f;
  const float C_E = 43.2808512266689f;    // CAP*log2(e)

  float lsum[2][4] = {{0, 0, 0, 0}, {0, 0, 0, 0}};

  // ---------------- pass 1: row sums of exp(capped_score - CAP) ----------------
  for (int t = 0; t < ntl; ++t) {
    const int kb = ks + t * 64;
#pragma unroll
    for (int ci = 0; ci < 4; ++ci) {
      const int call = w * 4 + ci;
      const int row = call * 4 + g;
      const int ch = c ^ (row & 7);
      gl16(kbp + (size_t)(kb + row) * DD + ch * 8, ldsK + call * 1024);
    }
    __syncthreads();

    f32x4 sc[2][4] = {};
#pragma unroll
    for (int nt = 0; nt < 4; ++nt) {
      const int row = nt * 16 + c;
#pragma unroll
      for (int kt = 0; kt < 4; ++kt) {
        const bf16x8 bk = *reinterpret_cast<const bf16x8*>(
            ldsK + row * 256 + (((kt * 4 + g) ^ (row & 7)) << 4));
        sc[0][nt] = __builtin_amdgcn_mfma_f32_16x16x32_bf16(aq[0][kt], bk, sc[0][nt], 0, 0, 0);
        sc[1][nt] = __builtin_amdgcn_mfma_f32_16x16x32_bf16(aq[1][kt], bk, sc[1][nt], 0, 0, 0);
      }
    }

#pragma unroll
    for (int mt = 0; mt < 2; ++mt) {
      const int imin = i0 + mt * 16;
#pragma unroll
      for (int nt = 0; nt < 4; ++nt) {
        const int jb = kb + nt * 16;
        if (jb > imin + 15 || jb + 15 < imin - WIN) continue;
        const bool needmask = (jb + 15 > imin) || (jb < imin + 15 - WIN);
        const int j = jb + c;
#pragma unroll
        for (int r = 0; r < 4; ++r) {
          const float x = sc[mt][nt][r];
          const float u = fmaf(x * x * (-C_T), x, x);   // 30*tanh(x/30) cubic
          float e = exp2f(fmaf(u, LOG2E, -C_E));
          if (needmask) {
            const int i = imin + g * 4 + r;
            e = (j <= i && j >= i - WIN) ? e : 0.0f;
          }
          lsum[mt][r] += e;
        }
      }
    }
    __syncthreads();
  }

  float ar[2][4];
#pragma unroll
  for (int mt = 0; mt < 2; ++mt)
#pragma unroll
    for (int r = 0; r < 4; ++r) {
      float l = lsum[mt][r];
      l += __shfl_xor(l, 1);
      l += __shfl_xor(l, 2);
      l += __shfl_xor(l, 4);
      l += __shfl_xor(l, 8);
      ar[mt][r] = 1.06f / l;
    }

  f32x4 acc[2][8] = {};

  // ---------------- pass 2: recompute scores, clip(probs), PV ----------------
  for (int t = 0; t < ntl; ++t) {
    const int kb = ks + t * 64;
#pragma unroll
    for (int ci = 0; ci < 4; ++ci) {
      const int call = w * 4 + ci;
      const int row = call * 4 + g;
      const int ch = c ^ (row & 7);
      gl16(kbp + (size_t)(kb + row) * DD + ch * 8, ldsK + call * 1024);
      const int vrow = call * 8 + (lane >> 3);
      const int vch = (lane & 7) ^ (vrow & 7);
      gl16(vbp + (size_t)vrow * SEQ + kb + vch * 8, ldsV + call * 1024);
    }
    __syncthreads();

    f32x4 sc[2][4] = {};
#pragma unroll
    for (int nt = 0; nt < 4; ++nt) {
      const int row = nt * 16 + c;
#pragma unroll
      for (int kt = 0; kt < 4; ++kt) {
        const bf16x8 bk = *reinterpret_cast<const bf16x8*>(
            ldsK + row * 256 + (((kt * 4 + g) ^ (row & 7)) << 4));
        sc[0][nt] = __builtin_amdgcn_mfma_f32_16x16x32_bf16(aq[0][kt], bk, sc[0][nt], 0, 0, 0);
        sc[1][nt] = __builtin_amdgcn_mfma_f32_16x16x32_bf16(aq[1][kt], bk, sc[1][nt], 0, 0, 0);
      }
    }

#pragma unroll
    for (int mt = 0; mt < 2; ++mt) {
      const int imin = i0 + mt * 16;
#pragma unroll
      for (int nt = 0; nt < 4; ++nt) {
        const int jb = kb + nt * 16;
        const bool inval = (jb > imin + 15) || (jb + 15 < imin - WIN);
        const bool needmask = (jb + 15 > imin) || (jb < imin + 15 - WIN);
        const int j = jb + c;
#pragma unroll
        for (int r = 0; r < 4; ++r) {
          const int prow = mt * 16 + g * 4 + r;
          const int pcol = nt * 16 + c;
          char* pa = ldsP + prow * 128 + (((pcol >> 3) ^ (prow & 7)) << 4) + (pcol & 7) * 2;
          u16 val = 0;
          if (!inval) {
            const float x = sc[mt][nt][r];
            const float u = fmaf(x * x * (-C_T), x, x);
            float e = exp2f(fmaf(u, LOG2E, -C_E));
            if (needmask) {
              const int i = imin + g * 4 + r;
              e = (j <= i && j >= i - WIN) ? e : 0.0f;
            }
            float p = fmaf(e, ar[mt][r], -0.03f);
            p = fminf(fmaxf(p, 0.0f), 1.0f);
            val = (u16)(__builtin_bit_cast(u32, p) >> 16);  // truncate to bf16 (p>=0)
          }
          *reinterpret_cast<u16*>(pa) = val;
        }
      }
    }

    // P fragments for PV (A operand): row=c, keys g*8+j
    bf16x8 pf[2][2];
#pragma unroll
    for (int mt = 0; mt < 2; ++mt)
#pragma unroll
      for (int k2 = 0; k2 < 2; ++k2) {
        const int prow = mt * 16 + c;
        pf[mt][k2] = *reinterpret_cast<const bf16x8*>(
            ldsP + prow * 128 + (((k2 * 4 + g) ^ (prow & 7)) << 4));
      }

#pragma unroll
    for (int dt = 0; dt < 8; ++dt) {
      const int vrow = dt * 16 + c;
#pragma unroll
      for (int k2 = 0; k2 < 2; ++k2) {
        const bf16x8 bv = *reinterpret_cast<const bf16x8*>(
            ldsV + vrow * 128 + (((k2 * 4 + g) ^ (vrow & 7)) << 4));
        acc[0][dt] = __builtin_amdgcn_mfma_f32_16x16x32_bf16(pf[0][k2], bv, acc[0][dt], 0, 0, 0);
        acc[1][dt] = __builtin_amdgcn_mfma_f32_16x16x32_bf16(pf[1][k2], bv, acc[1][dt], 0, 0, 0);
      }
    }
    __syncthreads();
  }

  // epilogue: out[b][i][h][d] fp32
#pragma unroll
  for (int mt = 0; mt < 2; ++mt)
#pragma unroll
    for (int r = 0; r < 4; ++r) {
      const int i = i0 + mt * 16 + g * 4 + r;
      float* op = out + (((size_t)b * SEQ + i) * HQ + h) * DD + c;
#pragma unroll
      for (int dt = 0; dt < 8; ++dt) op[dt * 16] = acc[mt][dt][r];
    }
}

extern "C" void kernel_launch(void* const* d_in, const int* in_sizes, int n_in,
                              void* d_out, int out_size, void* d_ws, size_t ws_size,
                              hipStream_t stream) {
  const float* q = (const float*)d_in[0];
  const float* k = (const float*)d_in[1];
  const float* v = (const float*)d_in[2];
  const float* qw = (const float*)d_in[3];
  const float* kw = (const float*)d_in[4];
  float* out = (float*)d_out;

  u16* qn = (u16*)d_ws;                                  // [2][32][2048][128] bf16
  u16* kn = qn + (size_t)2 * HQ * SEQ * DD;              // [2][8][2048][128] bf16
  u16* vt = kn + (size_t)2 * HKV * SEQ * DD;             // [2][8][128][2048] bf16

  norm_kernel<<<16384, 256, 0, stream>>>(q, qw, qn, 5, 0.08838834764831845f);
  norm_kernel<<<4096, 256, 0, stream>>>(k, kw, kn, 3, 1.0f);
  transv_kernel<<<512, 256, 0, stream>>>(v, vt);
  attn_kernel<<<1024, 256, 0, stream>>>(qn, kn, vt, out);
}

// Round 2
// 151.387 us; speedup vs baseline: 1.0745x; 1.0745x over previous
//
#include <hip/hip_runtime.h>

#define SEQ 2048
#define DD 128
#define HQ 32
#define HKV 8
#define WIN 512
#define QT 32

typedef unsigned short u16;
typedef unsigned int u32;
typedef __attribute__((ext_vector_type(8))) short bf16x8;
typedef __attribute__((ext_vector_type(4))) float f32x4;

__device__ __forceinline__ u16 f2bf(float f) {
  u32 u = __builtin_bit_cast(u32, f);
  u += 0x7FFFu + ((u >> 16) & 1u);
  return (u16)(u >> 16);
}

__device__ __forceinline__ void gl16(const void* g, void* l) {
  __builtin_amdgcn_global_load_lds(
      (const __attribute__((address_space(1))) void*)g,
      (__attribute__((address_space(3))) void*)l, 16, 0, 0);
}

__device__ __forceinline__ u32 cvtpk(float lo, float hi) {
  u32 r;
  asm("v_cvt_pk_bf16_f32 %0, %1, %2" : "=v"(r) : "v"(lo), "v"(hi));
  return r;
}

// GroupRMSNorm + weight + scale fold + bf16 + repack to [b][h][s][d]
__device__ __forceinline__ void norm_body(
    const float* __restrict__ x, const float* __restrict__ w,
    u16* __restrict__ o, int hshift, float scale, int blk, int tid) {
  const int lane = tid & 63;
  const int wv = tid >> 6;
  const int sub = lane >> 5;
  const int l5 = lane & 31;
  const int rid = blk * 8 + wv * 2 + sub;   // flattened (b,s,h)
  const int H = 1 << hshift;
  const int hh = rid & (H - 1);
  const int s = (rid >> hshift) & (SEQ - 1);
  const int b = rid >> (hshift + 11);
  const float4 xv = *(reinterpret_cast<const float4*>(x + (size_t)rid * DD) + l5);
  float ssq = xv.x * xv.x + xv.y * xv.y + xv.z * xv.z + xv.w * xv.w;
  ssq += __shfl_xor(ssq, 1);
  ssq += __shfl_xor(ssq, 2);
  ssq += __shfl_xor(ssq, 4);
  ssq += __shfl_xor(ssq, 8);
  ssq += __shfl_xor(ssq, 16);
  const float inv = rsqrtf(ssq * (1.0f / 128.0f) + 1e-5f) * scale;
  const float4 wv4 = *(reinterpret_cast<const float4*>(w + hh * DD) + l5);
  const u16 o0 = f2bf(xv.x * inv * wv4.x);
  const u16 o1 = f2bf(xv.y * inv * wv4.y);
  const u16 o2 = f2bf(xv.z * inv * wv4.z);
  const u16 o3 = f2bf(xv.w * inv * wv4.w);
  const size_t oo = (((size_t)b * H + hh) * SEQ + s) * DD + l5 * 4;
  uint2 pk;
  pk.x = (u32)o0 | ((u32)o1 << 16);
  pk.y = (u32)o2 | ((u32)o3 << 16);
  *reinterpret_cast<uint2*>(o + oo) = pk;
}

// V: fp32 [b][s][h][d] -> bf16 transposed [b][h][d][s]
__device__ __forceinline__ void transv_body(
    const float* __restrict__ v, u16* __restrict__ vt, int bid, int t) {
  const int st = bid & 31;
  const int h = (bid >> 5) & 7;
  const int b = bid >> 8;
  const int sbase = st * 64;
  const int d = t & 127;
  const int sch = (t >> 7) * 32;
  const size_t oo = (((size_t)(b * HKV + h)) * DD + d) * SEQ + sbase + sch;
#pragma unroll
  for (int q8 = 0; q8 < 4; ++q8) {
    uint4 o;
    u32 c[4];
#pragma unroll
    for (int p = 0; p < 4; ++p) {
      const int ss0 = q8 * 8 + p * 2;
      const int s0 = sbase + sch + ss0;
      const float a0 = v[((size_t)(b * SEQ + s0) * HKV + h) * DD + d];
      const float a1 = v[((size_t)(b * SEQ + s0 + 1) * HKV + h) * DD + d];
      c[p] = (u32)f2bf(a0) | ((u32)f2bf(a1) << 16);
    }
    o.x = c[0]; o.y = c[1]; o.z = c[2]; o.w = c[3];
    *reinterpret_cast<uint4*>(vt + oo + q8 * 8) = o;
  }
}

__global__ void __launch_bounds__(256) prep_kernel(
    const float* __restrict__ q, const float* __restrict__ k,
    const float* __restrict__ v, const float* __restrict__ qw,
    const float* __restrict__ kw, u16* __restrict__ qn,
    u16* __restrict__ kn, u16* __restrict__ vt) {
  const int blk = blockIdx.x;
  const int tid = threadIdx.x;
  if (blk < 16384) {
    norm_body(q, qw, qn, 5, 0.08838834764831845f, blk, tid);
  } else if (blk < 20480) {
    norm_body(k, kw, kn, 3, 1.0f, blk - 16384, tid);
  } else {
    transv_body(v, vt, blk - 20480, tid);
  }
}

__global__ void __launch_bounds__(256) attn_kernel(
    const u16* __restrict__ qn, const u16* __restrict__ kn,
    const u16* __restrict__ vt, float* __restrict__ out) {
  __shared__ char smem[32768];
  const int tid = threadIdx.x;
  const int w = tid >> 6;
  const int lane = tid & 63;
  const int c = lane & 15;
  const int g = lane >> 4;

  // XCD-locality remap: 1024 blocks, 8 XCDs -> each XCD owns 128 consecutive
  // logical blocks = 2 full (b,hk) K/V strips (~2MB, L2-resident).
  const int p = blockIdx.x;
  const int bid = ((p & 7) << 7) + (p >> 3);
  const int qt = bid & 63;
  const int hk = (bid >> 6) & 7;
  const int b = bid >> 9;
  const int i0 = qt * QT;
  const int h = hk * 4 + w;

  const u16* qb = qn + ((size_t)(b * HQ + h) * SEQ + i0) * DD;
  const u16* kbp = kn + (size_t)(b * HKV + hk) * SEQ * DD;
  const u16* vbp = vt + (size_t)(b * HKV + hk) * DD * SEQ;

  // Q fragments (used as MFMA B operand): col=c (query), k=g*8+j
  bf16x8 aq[2][4];
#pragma unroll
  for (int mt = 0; mt < 2; ++mt)
#pragma unroll
    for (int kt = 0; kt < 4; ++kt)
      aq[mt][kt] = *reinterpret_cast<const bf16x8*>(qb + (mt * 16 + c) * DD + kt * 32 + g * 8);

  int ks = i0 - WIN;
  ks = (ks < 0) ? 0 : (ks & ~63);
  const int ntl = (i0 + QT - ks + 63) >> 6;

  const float C_T = 3.70370370e-4f;       // 1/(3*CAP^2)
  const float LOG2E = 1.44269504088896f;
  const float C_E = 43.2808512266689f;    // CAP*log2(e)

  char* buf0 = smem;
  char* buf1 = smem + 16384;

  float lsum[2] = {0.0f, 0.0f};

  // ---------------- pass 1: row sums of exp(capped_score - CAP) ----------------
  // K double-buffered: stage t+1 while computing t; one barrier per iter.
  {
#pragma unroll
    for (int ci = 0; ci < 4; ++ci) {
      const int call = w * 4 + ci;
      const int row = call * 4 + g;
      const int ch = c ^ (row & 7);
      gl16(kbp + (size_t)(ks + row) * DD + ch * 8, buf0 + call * 1024);
    }
    __syncthreads();
  }
  for (int t = 0; t < ntl; ++t) {
    const int kb = ks + t * 64;
    char* cur = (t & 1) ? buf1 : buf0;
    char* nxt = (t & 1) ? buf0 : buf1;
    if (t + 1 < ntl) {
#pragma unroll
      for (int ci = 0; ci < 4; ++ci) {
        const int call = w * 4 + ci;
        const int row = call * 4 + g;
        const int ch = c ^ (row & 7);
        gl16(kbp + (size_t)(kb + 64 + row) * DD + ch * 8, nxt + call * 1024);
      }
    }

    f32x4 sc[2][4] = {};
#pragma unroll
    for (int nt = 0; nt < 4; ++nt) {
      const int row = nt * 16 + c;
      const int sw = row & 7;
#pragma unroll
      for (int kt = 0; kt < 4; ++kt) {
        const bf16x8 bk = *reinterpret_cast<const bf16x8*>(
            cur + row * 256 + (((kt * 4 + g) ^ sw) << 4));
        // swapped operands: S^T = K * Q  -> lane holds query col=c, keys 16nt+4g+r
        sc[0][nt] = __builtin_amdgcn_mfma_f32_16x16x32_bf16(bk, aq[0][kt], sc[0][nt], 0, 0, 0);
        sc[1][nt] = __builtin_amdgcn_mfma_f32_16x16x32_bf16(bk, aq[1][kt], sc[1][nt], 0, 0, 0);
      }
    }

#pragma unroll
    for (int mt = 0; mt < 2; ++mt) {
      const int imin = i0 + mt * 16;
      const int i = imin + c;
#pragma unroll
      for (int nt = 0; nt < 4; ++nt) {
        const int jb = kb + nt * 16;
        if (jb > imin + 15 || jb + 15 < imin - WIN) continue;
        const bool needmask = (jb + 15 > imin) || (jb < imin + 15 - WIN);
#pragma unroll
        for (int r = 0; r < 4; ++r) {
          const float x = sc[mt][nt][r];
          const float u = fmaf(x * x * (-C_T), x, x);   // 30*tanh(x/30) cubic
          float e = exp2f(fmaf(u, LOG2E, -C_E));
          if (needmask) {
            const int j = jb + g * 4 + r;
            e = (j <= i && j >= i - WIN) ? e : 0.0f;
          }
          lsum[mt] += e;
        }
      }
    }
    __syncthreads();
  }

  float ar[2];
#pragma unroll
  for (int mt = 0; mt < 2; ++mt) {
    float l = lsum[mt];
    l += __shfl_xor(l, 16);
    l += __shfl_xor(l, 32);
    ar[mt] = 1.06f / l;
  }

  f32x4 acc[2][8] = {};
  char* ldsK = buf0;
  char* ldsV = buf1;
  const int sl0 = c + ((g & 1) << 5);
  const bool hig = (g >> 1) != 0;

  // ---------------- pass 2: recompute scores, clip(probs), PV ----------------
  for (int t = 0; t < ntl; ++t) {
    const int kb = ks + t * 64;
#pragma unroll
    for (int ci = 0; ci < 4; ++ci) {
      const int call = w * 4 + ci;
      const int row = call * 4 + g;
      const int ch = c ^ (row & 7);
      gl16(kbp + (size_t)(kb + row) * DD + ch * 8, ldsK + call * 1024);
      const int vrow = call * 8 + (lane >> 3);
      const int vch = (lane & 7) ^ (vrow & 7);
      gl16(vbp + (size_t)vrow * SEQ + kb + vch * 8, ldsV + call * 1024);
    }
    __syncthreads();

    f32x4 sc[2][4] = {};
#pragma unroll
    for (int nt = 0; nt < 4; ++nt) {
      const int row = nt * 16 + c;
      const int sw = row & 7;
#pragma unroll
      for (int kt = 0; kt < 4; ++kt) {
        const bf16x8 bk = *reinterpret_cast<const bf16x8*>(
            ldsK + row * 256 + (((kt * 4 + g) ^ sw) << 4));
        sc[0][nt] = __builtin_amdgcn_mfma_f32_16x16x32_bf16(bk, aq[0][kt], sc[0][nt], 0, 0, 0);
        sc[1][nt] = __builtin_amdgcn_mfma_f32_16x16x32_bf16(bk, aq[1][kt], sc[1][nt], 0, 0, 0);
      }
    }

    // probs -> packed bf16 pairs, in-register
    u32 pk[2][4][2];
#pragma unroll
    for (int mt = 0; mt < 2; ++mt) {
      const int imin = i0 + mt * 16;
      const int i = imin + c;
#pragma unroll
      for (int nt = 0; nt < 4; ++nt) {
        const int jb = kb + nt * 16;
        const bool inval = (jb > imin + 15) || (jb + 15 < imin - WIN);
        const bool needmask = (jb + 15 > imin) || (jb < imin + 15 - WIN);
        float pv4[4];
#pragma unroll
        for (int r = 0; r < 4; ++r) {
          float e;
          if (inval) {
            e = 0.0f;
          } else {
            const float x = sc[mt][nt][r];
            const float u = fmaf(x * x * (-C_T), x, x);
            e = exp2f(fmaf(u, LOG2E, -C_E));
            if (needmask) {
              const int j = jb + g * 4 + r;
              e = (j <= i && j >= i - WIN) ? e : 0.0f;
            }
          }
          float pp = fmaf(e, ar[mt], -0.03f);
          pv4[r] = fminf(fmaxf(pp, 0.0f), 1.0f);
        }
        pk[mt][nt][0] = cvtpk(pv4[0], pv4[1]);
        pk[mt][nt][1] = cvtpk(pv4[2], pv4[3]);
      }
    }

    // exchange: build PV A-fragments. Target lane (c,g) word u holds keys
    // 32*k2 + 8*g + 2u(+1); source lane (c, 2*(g&1)+(u>>1)), subtile 2*k2+(g>>1).
    union PU { bf16x8 v; u32 w4[4]; };
    PU pf[2][2];
#pragma unroll
    for (int mt = 0; mt < 2; ++mt)
#pragma unroll
      for (int k2 = 0; k2 < 2; ++k2)
#pragma unroll
        for (int u = 0; u < 4; ++u) {
          const int srcl = sl0 + ((u >> 1) << 4);
          const u32 va = (u32)__shfl((int)pk[mt][2 * k2][u & 1], srcl, 64);
          const u32 vb = (u32)__shfl((int)pk[mt][2 * k2 + 1][u & 1], srcl, 64);
          pf[mt][k2].w4[u] = hig ? vb : va;
        }

#pragma unroll
    for (int dt = 0; dt < 8; ++dt) {
      const int rv = dt * 16 + c;
      const int sw = rv & 7;
#pragma unroll
      for (int k2 = 0; k2 < 2; ++k2) {
        const bf16x8 bv = *reinterpret_cast<const bf16x8*>(
            ldsV + rv * 128 + (((k2 * 4 + g) ^ sw) << 4));
        acc[0][dt] = __builtin_amdgcn_mfma_f32_16x16x32_bf16(pf[0][k2].v, bv, acc[0][dt], 0, 0, 0);
        acc[1][dt] = __builtin_amdgcn_mfma_f32_16x16x32_bf16(pf[1][k2].v, bv, acc[1][dt], 0, 0, 0);
      }
    }
    __syncthreads();
  }

  // epilogue: out[b][i][h][d] fp32; query = i0+16mt+4g+r, dim = 16dt+c
#pragma unroll
  for (int mt = 0; mt < 2; ++mt)
#pragma unroll
    for (int r = 0; r < 4; ++r) {
      const int i = i0 + mt * 16 + g * 4 + r;
      float* op = out + (((size_t)b * SEQ + i) * HQ + h) * DD + c;
#pragma unroll
      for (int dt = 0; dt < 8; ++dt) op[dt * 16] = acc[mt][dt][r];
    }
}

extern "C" void kernel_launch(void* const* d_in, const int* in_sizes, int n_in,
                              void* d_out, int out_size, void* d_ws, size_t ws_size,
                              hipStream_t stream) {
  const float* q = (const float*)d_in[0];
  const float* k = (const float*)d_in[1];
  const float* v = (const float*)d_in[2];
  const float* qw = (const float*)d_in[3];
  const float* kw = (const float*)d_in[4];
  float* out = (float*)d_out;

  u16* qn = (u16*)d_ws;                                  // [2][32][2048][128] bf16
  u16* kn = qn + (size_t)2 * HQ * SEQ * DD;              // [2][8][2048][128] bf16
  u16* vt = kn + (size_t)2 * HKV * SEQ * DD;             // [2][8][128][2048] bf16

  prep_kernel<<<20992, 256, 0, stream>>>(q, k, v, qw, kw, qn, kn, vt);
  attn_kernel<<<1024, 256, 0, stream>>>(qn, kn, vt, out);
}